// Round 3
// baseline (1558.334 us; speedup 1.0000x reference)
//
#include <hip/hip_runtime.h>

#define NN 50000
#define NE 800000
#define CC 128
#define NL 3

__device__ __forceinline__ float b2f(unsigned short u) {
  return __uint_as_float(((unsigned int)u) << 16);
}
__device__ __forceinline__ unsigned short f2b(float f) {
  unsigned int x = __float_as_uint(f);
  x += 0x7fffu + ((x >> 16) & 1u);   // round-to-nearest-even
  return (unsigned short)(x >> 16);
}
__device__ __forceinline__ void atomAdd(float* p, float v) {
  __hip_atomic_fetch_add(p, v, __ATOMIC_RELAXED, __HIP_MEMORY_SCOPE_AGENT);
}

// flags[0] = 1 if float tensors are bf16, 0 if f32.
// flags[1] = 1 if edge_index is int64 (odd 32-bit words all zero), 0 if int32.
__global__ void k_flags(const unsigned short* __restrict__ x,
                        const int* __restrict__ ei, int* __restrict__ flags) {
  __shared__ int cnt, any;
  if (threadIdx.x == 0) { cnt = 0; any = 0; }
  __syncthreads();
  if (threadIdx.x < 128) {
    unsigned short u = x[2 * threadIdx.x];      // even 16b words of x
    int ex = (u >> 7) & 0xFF;                   // bf16 exponent field
    if (ex >= 0x70 && ex <= 0x8F) atomicAdd(&cnt, 1);
  }
  if (ei[2 * threadIdx.x + 1] != 0) atomicOr(&any, 1);
  __syncthreads();
  if (threadIdx.x == 0) {
    flags[0] = (cnt >= 64) ? 1 : 0;   // bf16 N(0,1): ~128 hits; f32 mantissa: ~16
    flags[1] = (any == 0) ? 1 : 0;
  }
}

__device__ __forceinline__ int eidx(const int* ei, int row, int e, int f64) {
  return f64 ? ei[2 * ((size_t)row * NE + e)] : ei[(size_t)row * NE + e];
}

// ---- x (bf16 or f32) -> f32 workspace, 4 elems/thread ----
__global__ __launch_bounds__(256) void k_cvt_x(const void* __restrict__ xin,
                                               float* __restrict__ xf,
                                               const int* __restrict__ flags) {
  int i = blockIdx.x * 256 + threadIdx.x;   // exactly NN*CC/4 threads
  if (flags[0]) {
    const ushort4 v = ((const ushort4*)xin)[i];
    ((float4*)xf)[i] = make_float4(b2f(v.x), b2f(v.y), b2f(v.z), b2f(v.w));
  } else {
    ((float4*)xf)[i] = ((const float4*)xin)[i];
  }
}

// ---- params (lw, lb, emw, emb) -> f32 workspace ----
__global__ __launch_bounds__(256) void k_cvt_par(const void* lw, const void* lb,
                                                 const void* emw, const void* emb,
                                                 float* lwf, float* lbf,
                                                 float* emwf, float* embf,
                                                 const int* __restrict__ flags) {
  int i = blockIdx.x * 256 + threadIdx.x;
  const int bf = flags[0];
  if (i < NL * CC * CC)
    lwf[i] = bf ? b2f(((const unsigned short*)lw)[i]) : ((const float*)lw)[i];
  if (i < NL * CC)
    lbf[i] = bf ? b2f(((const unsigned short*)lb)[i]) : ((const float*)lb)[i];
  if (i < NL * 8)
    emwf[i] = bf ? b2f(((const unsigned short*)emw)[i]) : ((const float*)emw)[i];
  if (i < NL)
    embf[i] = bf ? b2f(((const unsigned short*)emb)[i]) : ((const float*)emb)[i];
}

// ---- per-edge weight: softplus(edge_attr . ew + eb); also S[dst] += w ----
__global__ __launch_bounds__(256) void k_edgew(const void* __restrict__ ea,
                                               const int* __restrict__ ei,
                                               const float* __restrict__ emwf,
                                               const float* __restrict__ embf,
                                               int layer,
                                               float* __restrict__ wbuf,
                                               float* __restrict__ S,
                                               const int* __restrict__ flags) {
  int e = blockIdx.x * 256 + threadIdx.x;
  if (e >= NE) return;
  float a[8];
  if (flags[0]) {                       // bf16: 8 attrs in 16B
    const uint4 v = ((const uint4*)ea)[e];
    unsigned int p[4] = {v.x, v.y, v.z, v.w};
#pragma unroll
    for (int q = 0; q < 4; ++q) {
      a[2 * q]     = __uint_as_float(p[q] << 16);
      a[2 * q + 1] = __uint_as_float(p[q] & 0xffff0000u);
    }
  } else {                              // f32: 8 attrs in 32B
    const float4 v0 = ((const float4*)ea)[2 * e];
    const float4 v1 = ((const float4*)ea)[2 * e + 1];
    a[0] = v0.x; a[1] = v0.y; a[2] = v0.z; a[3] = v0.w;
    a[4] = v1.x; a[5] = v1.y; a[6] = v1.z; a[7] = v1.w;
  }
  float z = embf[layer];
#pragma unroll
  for (int k = 0; k < 8; ++k) z += a[k] * emwf[layer * 8 + k];
  float w = (z > 20.f) ? z : log1pf(expf(z));   // softplus
  wbuf[e] = w;
  atomAdd(&S[eidx(ei, 1, e, flags[1])], w);
}

// ---- scatter: agg[dst] += w * x[src]  (one block = 128 channels of one edge) ----
__global__ __launch_bounds__(128) void k_scatter(const int* __restrict__ ei,
                                                 const float* __restrict__ wbuf,
                                                 const float* __restrict__ xf,
                                                 float* __restrict__ agg,
                                                 const int* __restrict__ flags) {
  const int c = threadIdx.x;
  const int f64 = flags[1];
  for (int e = blockIdx.x; e < NE; e += gridDim.x) {
    const int s = eidx(ei, 0, e, f64);   // wave-uniform -> scalar load
    const int d = eidx(ei, 1, e, f64);
    const float w = wbuf[e];
    atomAdd(&agg[(size_t)d * CC + c], w * xf[(size_t)s * CC + c]);
  }
}

// ---- fused: y = (agg - S*x) @ lw + lb ; relu+residual in-place into agg,
//      or (last) store to d_out in detected dtype.
// block = 256 threads, tile = 16 rows x 128 cols; thread: 2 rows x 4 cols.
// In-place write into agg is safe: each block stages its own 16 rows to LDS
// before __syncthreads, and only its own rows are overwritten after.
__global__ __launch_bounds__(256) void k_gemm(float* agg,
                                              const float* __restrict__ S,
                                              const float* __restrict__ xc,
                                              const float* __restrict__ lwf,
                                              const float* __restrict__ lbf,
                                              int layer, void* outp, int last,
                                              const int* __restrict__ flags) {
  __shared__ float wsh[CC * CC];   // 64 KB f32 weights
  __shared__ float ash[16 * CC];   // 8 KB staged a = agg - S*x
  const float* lwp = lwf + (size_t)layer * CC * CC;
  for (int i = threadIdx.x; i < CC * CC / 4; i += 256)
    ((float4*)wsh)[i] = ((const float4*)lwp)[i];

  const int cg = threadIdx.x & 31;   // 4 cols at cg*4
  const int rs = threadIdx.x >> 5;   // row slot 0..7 (rows rs and rs+8)
  const int rb = blockIdx.x * 16;

  for (int i = threadIdx.x; i < 16 * CC / 4; i += 256) {
    const int idx = i << 2;
    const int gr = rb + (idx >> 7);
    const int k = idx & (CC - 1);
    const float s = S[gr];
    const float4 av = *(const float4*)&agg[(size_t)gr * CC + k];
    const float4 xv = *(const float4*)&xc[(size_t)gr * CC + k];
    *(float4*)&ash[idx] = make_float4(av.x - s * xv.x, av.y - s * xv.y,
                                      av.z - s * xv.z, av.w - s * xv.w);
  }
  __syncthreads();

  float c0x = 0, c0y = 0, c0z = 0, c0w = 0;
  float c1x = 0, c1y = 0, c1z = 0, c1w = 0;
#pragma unroll 4
  for (int k = 0; k < CC; ++k) {
    const float a0 = ash[rs * CC + k];
    const float a1 = ash[(rs + 8) * CC + k];
    const float4 w = *(const float4*)&wsh[k * CC + (cg << 2)];
    c0x += a0 * w.x; c0y += a0 * w.y; c0z += a0 * w.z; c0w += a0 * w.w;
    c1x += a1 * w.x; c1y += a1 * w.y; c1z += a1 * w.z; c1w += a1 * w.w;
  }

  const float* lbp = lbf + layer * CC + (cg << 2);
  const float b0 = lbp[0], b1 = lbp[1], b2v = lbp[2], b3 = lbp[3];
  const int isbf = flags[0];

#pragma unroll
  for (int h = 0; h < 2; ++h) {
    const int r = rb + rs + h * 8;
    float y0 = (h ? c1x : c0x) + b0;
    float y1 = (h ? c1y : c0y) + b1;
    float y2 = (h ? c1z : c0z) + b2v;
    float y3 = (h ? c1w : c0w) + b3;
    const size_t off = (size_t)r * CC + (cg << 2);
    if (!last) {
      const float4 rv = *(const float4*)&xc[off];   // residual (other buffer)
      *(float4*)&agg[off] = make_float4(fmaxf(y0, 0.f) + rv.x, fmaxf(y1, 0.f) + rv.y,
                                        fmaxf(y2, 0.f) + rv.z, fmaxf(y3, 0.f) + rv.w);
    } else if (isbf) {
      *(uint2*)&((unsigned short*)outp)[off] =
          make_uint2((unsigned)f2b(y0) | ((unsigned)f2b(y1) << 16),
                     (unsigned)f2b(y2) | ((unsigned)f2b(y3) << 16));
    } else {
      *(float4*)&((float*)outp)[off] = make_float4(y0, y1, y2, y3);
    }
  }
}

extern "C" void kernel_launch(void* const* d_in, const int* in_sizes, int n_in,
                              void* d_out, int out_size, void* d_ws, size_t ws_size,
                              hipStream_t stream) {
  const unsigned short* x0 = (const unsigned short*)d_in[0];
  const int* ei = (const int*)d_in[1];

  // f32 workspace layout: buf0 | buf1 | S | wbuf | lwf | lbf | emwf | embf | flags
  const size_t nbuf = (size_t)NN * CC;
  size_t need = (nbuf * 2 + NN + NE + (size_t)NL * CC * CC + NL * CC + NL * 8 + NL) * 4
                + 2 * sizeof(int) + 64;
  if (ws_size < need) {
    // diagnostic fallback: zero output (non-NaN signature absmax == max|ref|)
    hipMemsetAsync(d_out, 0, (size_t)out_size * 2, stream);
    return;
  }
  float* buf0 = (float*)d_ws;
  float* buf1 = buf0 + nbuf;
  float* S = buf1 + nbuf;
  float* wbuf = S + NN;
  float* lwf = wbuf + NE;
  float* lbf = lwf + (size_t)NL * CC * CC;
  float* emwf = lbf + NL * CC;
  float* embf = emwf + NL * 8;
  int* flags = (int*)(embf + NL);

  k_flags<<<1, 256, 0, stream>>>(x0, ei, flags);
  k_cvt_x<<<(NN * CC / 4) / 256, 256, 0, stream>>>(d_in[0], buf0, flags);
  k_cvt_par<<<(NL * CC * CC + 255) / 256, 256, 0, stream>>>(
      d_in[3], d_in[4], d_in[5], d_in[6], lwf, lbf, emwf, embf, flags);

  float* xc = buf0;   // current x
  float* ag = buf1;   // accumulator buffer for this layer
  for (int layer = 0; layer < NL; ++layer) {
    hipMemsetAsync(ag, 0, nbuf * sizeof(float), stream);
    hipMemsetAsync(S, 0, NN * sizeof(float), stream);
    k_edgew<<<(NE + 255) / 256, 256, 0, stream>>>(d_in[2], ei, emwf, embf, layer,
                                                  wbuf, S, flags);
    k_scatter<<<8192, 128, 0, stream>>>(ei, wbuf, xc, ag, flags);
    k_gemm<<<NN / 16, 256, 0, stream>>>(ag, S, xc, lwf, lbf, layer, d_out,
                                        layer == NL - 1 ? 1 : 0, flags);
    // gemm wrote new x in-place into ag (non-last layers); swap roles
    float* t = xc; xc = ag; ag = t;
  }
}

// Round 4
// 714.834 us; speedup vs baseline: 2.1800x; 2.1800x over previous
//
#include <hip/hip_runtime.h>

#define NN 50000
#define NE 800000
#define CC 128
#define NL 3

__device__ __forceinline__ float b2f(unsigned short u) {
  return __uint_as_float(((unsigned int)u) << 16);
}
__device__ __forceinline__ unsigned short f2b(float f) {
  unsigned int x = __float_as_uint(f);
  x += 0x7fffu + ((x >> 16) & 1u);   // round-to-nearest-even
  return (unsigned short)(x >> 16);
}

// flags[0] = 1 if float tensors are bf16, 0 if f32.
// flags[1] = 1 if edge_index is int64 (odd 32-bit words all zero), 0 if int32.
__global__ void k_flags(const unsigned short* __restrict__ x,
                        const int* __restrict__ ei, int* __restrict__ flags) {
  __shared__ int cnt, any;
  if (threadIdx.x == 0) { cnt = 0; any = 0; }
  __syncthreads();
  if (threadIdx.x < 128) {
    unsigned short u = x[2 * threadIdx.x];      // even 16b words of x
    int ex = (u >> 7) & 0xFF;                   // bf16 exponent field
    if (ex >= 0x70 && ex <= 0x8F) atomicAdd(&cnt, 1);
  }
  if (ei[2 * threadIdx.x + 1] != 0) atomicOr(&any, 1);
  __syncthreads();
  if (threadIdx.x == 0) {
    flags[0] = (cnt >= 64) ? 1 : 0;
    flags[1] = (any == 0) ? 1 : 0;
  }
}

__device__ __forceinline__ int eidx(const int* ei, int row, int e, int f64) {
  return f64 ? ei[2 * ((size_t)row * NE + e)] : ei[(size_t)row * NE + e];
}

// ---- x (bf16 or f32) -> f32 workspace, 4 elems/thread ----
__global__ __launch_bounds__(256) void k_cvt_x(const void* __restrict__ xin,
                                               float* __restrict__ xf,
                                               const int* __restrict__ flags) {
  int i = blockIdx.x * 256 + threadIdx.x;   // exactly NN*CC/4 threads
  if (flags[0]) {
    const ushort4 v = ((const ushort4*)xin)[i];
    ((float4*)xf)[i] = make_float4(b2f(v.x), b2f(v.y), b2f(v.z), b2f(v.w));
  } else {
    ((float4*)xf)[i] = ((const float4*)xin)[i];
  }
}

// ---- params (lw, lb, emw, emb) -> f32 workspace ----
__global__ __launch_bounds__(256) void k_cvt_par(const void* lw, const void* lb,
                                                 const void* emw, const void* emb,
                                                 float* lwf, float* lbf,
                                                 float* emwf, float* embf,
                                                 const int* __restrict__ flags) {
  int i = blockIdx.x * 256 + threadIdx.x;
  const int bf = flags[0];
  if (i < NL * CC * CC)
    lwf[i] = bf ? b2f(((const unsigned short*)lw)[i]) : ((const float*)lw)[i];
  if (i < NL * CC)
    lbf[i] = bf ? b2f(((const unsigned short*)lb)[i]) : ((const float*)lb)[i];
  if (i < NL * 8)
    emwf[i] = bf ? b2f(((const unsigned short*)emw)[i]) : ((const float*)emw)[i];
  if (i < NL)
    embf[i] = bf ? b2f(((const unsigned short*)emb)[i]) : ((const float*)emb)[i];
}

// ---- CSR build: histogram of dst ----
__global__ __launch_bounds__(256) void k_hist(const int* __restrict__ ei,
                                              int* __restrict__ deg,
                                              const int* __restrict__ flags) {
  int e = blockIdx.x * 256 + threadIdx.x;
  if (e >= NE) return;
  atomicAdd(&deg[eidx(ei, 1, e, flags[1])], 1);
}

// ---- CSR build: 1-block hierarchical exclusive scan over deg[NN] ----
#define CHUNK 49
__global__ __launch_bounds__(1024) void k_scan(const int* __restrict__ deg,
                                               int* __restrict__ offs,
                                               int* __restrict__ cursor) {
  __shared__ int ls[1024];
  const int t = threadIdx.x;
  const int base = t * CHUNK;
  int s = 0;
  for (int i = 0; i < CHUNK; ++i) {
    int idx = base + i;
    if (idx < NN) s += deg[idx];
  }
  ls[t] = s;
  __syncthreads();
  for (int off = 1; off < 1024; off <<= 1) {
    int tmp = (t >= off) ? ls[t - off] : 0;
    __syncthreads();
    ls[t] += tmp;
    __syncthreads();
  }
  int run = ls[t] - s;   // exclusive prefix of this chunk
  for (int i = 0; i < CHUNK; ++i) {
    int idx = base + i;
    if (idx < NN) {
      offs[idx] = run;
      cursor[idx] = run;
      run += deg[idx];
    }
  }
  if (t == 1023) offs[NN] = ls[1023];
}

// ---- CSR build: fill sorted src + per-edge rank ----
__global__ __launch_bounds__(256) void k_fill(const int* __restrict__ ei,
                                              int* __restrict__ cursor,
                                              int* __restrict__ rank,
                                              int* __restrict__ srcs,
                                              const int* __restrict__ flags) {
  int e = blockIdx.x * 256 + threadIdx.x;
  if (e >= NE) return;
  const int f64 = flags[1];
  int d = eidx(ei, 1, e, f64);
  int pos = atomicAdd(&cursor[d], 1);
  rank[e] = pos;
  srcs[pos] = eidx(ei, 0, e, f64);
}

// ---- per-edge weight: softplus(edge_attr . ew + eb) -> w_sorted[rank[e]] ----
__global__ __launch_bounds__(256) void k_edgew(const void* __restrict__ ea,
                                               const float* __restrict__ emwf,
                                               const float* __restrict__ embf,
                                               int layer,
                                               const int* __restrict__ rank,
                                               float* __restrict__ wsorted,
                                               const int* __restrict__ flags) {
  int e = blockIdx.x * 256 + threadIdx.x;
  if (e >= NE) return;
  float a[8];
  if (flags[0]) {                       // bf16: 8 attrs in 16B
    const uint4 v = ((const uint4*)ea)[e];
    unsigned int p[4] = {v.x, v.y, v.z, v.w};
#pragma unroll
    for (int q = 0; q < 4; ++q) {
      a[2 * q]     = __uint_as_float(p[q] << 16);
      a[2 * q + 1] = __uint_as_float(p[q] & 0xffff0000u);
    }
  } else {                              // f32: 8 attrs in 32B
    const float4 v0 = ((const float4*)ea)[2 * e];
    const float4 v1 = ((const float4*)ea)[2 * e + 1];
    a[0] = v0.x; a[1] = v0.y; a[2] = v0.z; a[3] = v0.w;
    a[4] = v1.x; a[5] = v1.y; a[6] = v1.z; a[7] = v1.w;
  }
  float z = embf[layer];
#pragma unroll
  for (int k = 0; k < 8; ++k) z += a[k] * emwf[layer * 8 + k];
  float w = (z > 20.f) ? z : log1pf(expf(z));   // softplus
  wsorted[rank[e]] = w;
}

// ---- gather: agg[n] = sum_{dst=n} w*x[src] - (sum w)*x[n]  (one wave/node) ----
__global__ __launch_bounds__(256) void k_gather(const int* __restrict__ offs,
                                                const int* __restrict__ srcs,
                                                const float* __restrict__ ws,
                                                const float* __restrict__ xf,
                                                float* __restrict__ agg) {
  const int node = blockIdx.x * 4 + (threadIdx.x >> 6);
  if (node >= NN) return;
  const int c = (threadIdx.x & 63) * 2;
  float ax = 0.f, ay = 0.f, sw = 0.f;
  int j = offs[node];
  const int j1 = offs[node + 1];
  for (; j + 1 < j1; j += 2) {          // 2-edge unroll for MLP
    const int s0 = srcs[j], s1 = srcs[j + 1];          // wave-uniform
    const float w0 = ws[j], w1 = ws[j + 1];
    const float2 v0 = *(const float2*)&xf[(size_t)s0 * CC + c];
    const float2 v1 = *(const float2*)&xf[(size_t)s1 * CC + c];
    ax += w0 * v0.x + w1 * v1.x;
    ay += w0 * v0.y + w1 * v1.y;
    sw += w0 + w1;
  }
  if (j < j1) {
    const int s0 = srcs[j];
    const float w0 = ws[j];
    const float2 v0 = *(const float2*)&xf[(size_t)s0 * CC + c];
    ax += w0 * v0.x; ay += w0 * v0.y; sw += w0;
  }
  const float2 xi = *(const float2*)&xf[(size_t)node * CC + c];
  *(float2*)&agg[(size_t)node * CC + c] = make_float2(ax - sw * xi.x, ay - sw * xi.y);
}

// ---- gemm: y = agg @ lw + lb ; relu+residual in-place into agg,
//      or (last) store to d_out in detected dtype.
__global__ __launch_bounds__(256) void k_gemm(float* agg,
                                              const float* __restrict__ xc,
                                              const float* __restrict__ lwf,
                                              const float* __restrict__ lbf,
                                              int layer, void* outp, int last,
                                              const int* __restrict__ flags) {
  __shared__ float wsh[CC * CC];   // 64 KB f32 weights
  __shared__ float ash[16 * CC];   // 8 KB staged agg rows
  const float* lwp = lwf + (size_t)layer * CC * CC;
  for (int i = threadIdx.x; i < CC * CC / 4; i += 256)
    ((float4*)wsh)[i] = ((const float4*)lwp)[i];

  const int cg = threadIdx.x & 31;   // 4 cols at cg*4
  const int rs = threadIdx.x >> 5;   // row slot 0..7 (rows rs and rs+8)
  const int rb = blockIdx.x * 16;

  for (int i = threadIdx.x; i < 16 * CC / 4; i += 256)
    ((float4*)ash)[i] = *(const float4*)&agg[(size_t)rb * CC + (i << 2)];
  __syncthreads();

  float c0x = 0, c0y = 0, c0z = 0, c0w = 0;
  float c1x = 0, c1y = 0, c1z = 0, c1w = 0;
#pragma unroll 4
  for (int k = 0; k < CC; ++k) {
    const float a0 = ash[rs * CC + k];
    const float a1 = ash[(rs + 8) * CC + k];
    const float4 w = *(const float4*)&wsh[k * CC + (cg << 2)];
    c0x += a0 * w.x; c0y += a0 * w.y; c0z += a0 * w.z; c0w += a0 * w.w;
    c1x += a1 * w.x; c1y += a1 * w.y; c1z += a1 * w.z; c1w += a1 * w.w;
  }

  const float* lbp = lbf + layer * CC + (cg << 2);
  const float b0 = lbp[0], b1 = lbp[1], b2v = lbp[2], b3 = lbp[3];
  const int isbf = flags[0];

#pragma unroll
  for (int h = 0; h < 2; ++h) {
    const int r = rb + rs + h * 8;
    float y0 = (h ? c1x : c0x) + b0;
    float y1 = (h ? c1y : c0y) + b1;
    float y2 = (h ? c1z : c0z) + b2v;
    float y3 = (h ? c1w : c0w) + b3;
    const size_t off = (size_t)r * CC + (cg << 2);
    if (!last) {
      const float4 rv = *(const float4*)&xc[off];   // residual
      *(float4*)&agg[off] = make_float4(fmaxf(y0, 0.f) + rv.x, fmaxf(y1, 0.f) + rv.y,
                                        fmaxf(y2, 0.f) + rv.z, fmaxf(y3, 0.f) + rv.w);
    } else if (isbf) {
      *(uint2*)&((unsigned short*)outp)[off] =
          make_uint2((unsigned)f2b(y0) | ((unsigned)f2b(y1) << 16),
                     (unsigned)f2b(y2) | ((unsigned)f2b(y3) << 16));
    } else {
      *(float4*)&((float*)outp)[off] = make_float4(y0, y1, y2, y3);
    }
  }
}

extern "C" void kernel_launch(void* const* d_in, const int* in_sizes, int n_in,
                              void* d_out, int out_size, void* d_ws, size_t ws_size,
                              hipStream_t stream) {
  const unsigned short* x0 = (const unsigned short*)d_in[0];
  const int* ei = (const int*)d_in[1];

  const size_t nbuf = (size_t)NN * CC;
  const size_t need = (nbuf * 2 + (size_t)NL * CC * CC + NL * CC + NL * 8 + NL
                       + NE              // w_sorted
                       + NN + (NN + 1) + NN   // deg, offs, cursor
                       + NE + NE              // rank, srcs
                       + 2) * 4 + 64;
  if (ws_size < need) {
    hipMemsetAsync(d_out, 0, (size_t)out_size * 2, stream);
    return;
  }
  float* buf0 = (float*)d_ws;
  float* buf1 = buf0 + nbuf;
  float* lwf = buf1 + nbuf;
  float* lbf = lwf + (size_t)NL * CC * CC;
  float* emwf = lbf + (size_t)NL * CC;
  float* embf = emwf + NL * 8;
  float* wsorted = embf + NL;
  int* deg = (int*)(wsorted + NE);
  int* offs = deg + NN;
  int* cursor = offs + NN + 1;
  int* rank = cursor + NN;
  int* srcs = rank + NE;
  int* flags = srcs + NE;

  k_flags<<<1, 256, 0, stream>>>(x0, ei, flags);
  k_cvt_x<<<(NN * CC / 4) / 256, 256, 0, stream>>>(d_in[0], buf0, flags);
  k_cvt_par<<<(NL * CC * CC + 255) / 256, 256, 0, stream>>>(
      d_in[3], d_in[4], d_in[5], d_in[6], lwf, lbf, emwf, embf, flags);

  // CSR build (once per call; edge_index is call-invariant)
  hipMemsetAsync(deg, 0, NN * sizeof(int), stream);
  k_hist<<<(NE + 255) / 256, 256, 0, stream>>>(ei, deg, flags);
  k_scan<<<1, 1024, 0, stream>>>(deg, offs, cursor);
  k_fill<<<(NE + 255) / 256, 256, 0, stream>>>(ei, cursor, rank, srcs, flags);

  float* xc = buf0;   // current x
  float* ag = buf1;   // message buffer for this layer
  for (int layer = 0; layer < NL; ++layer) {
    k_edgew<<<(NE + 255) / 256, 256, 0, stream>>>(d_in[2], emwf, embf, layer,
                                                  rank, wsorted, flags);
    k_gather<<<(NN + 3) / 4, 256, 0, stream>>>(offs, srcs, wsorted, xc, ag);
    k_gemm<<<NN / 16, 256, 0, stream>>>(ag, xc, lwf, lbf, layer, d_out,
                                        layer == NL - 1 ? 1 : 0, flags);
    float* t = xc; xc = ag; ag = t;   // gemm wrote new x in-place into ag
  }
}

// Round 5
// 574.840 us; speedup vs baseline: 2.7109x; 1.2435x over previous
//
#include <hip/hip_runtime.h>

#define NN 50000
#define NE 800000
#define CC 128
#define NL 3

__device__ __forceinline__ float b2f(unsigned short u) {
  return __uint_as_float(((unsigned int)u) << 16);
}
__device__ __forceinline__ unsigned short f2b(float f) {
  unsigned int x = __float_as_uint(f);
  x += 0x7fffu + ((x >> 16) & 1u);   // round-to-nearest-even
  return (unsigned short)(x >> 16);
}

// flags[0] = 1 if float tensors are bf16, 0 if f32.
// flags[1] = 1 if edge_index is int64 (odd 32-bit words all zero), 0 if int32.
__global__ void k_flags(const unsigned short* __restrict__ x,
                        const int* __restrict__ ei, int* __restrict__ flags) {
  __shared__ int cnt, any;
  if (threadIdx.x == 0) { cnt = 0; any = 0; }
  __syncthreads();
  if (threadIdx.x < 128) {
    unsigned short u = x[2 * threadIdx.x];      // even 16b words of x
    int ex = (u >> 7) & 0xFF;                   // bf16 exponent field
    if (ex >= 0x70 && ex <= 0x8F) atomicAdd(&cnt, 1);
  }
  if (ei[2 * threadIdx.x + 1] != 0) atomicOr(&any, 1);
  __syncthreads();
  if (threadIdx.x == 0) {
    flags[0] = (cnt >= 64) ? 1 : 0;
    flags[1] = (any == 0) ? 1 : 0;
  }
}

__device__ __forceinline__ int eidx(const int* ei, int row, int e, int f64) {
  return f64 ? ei[2 * ((size_t)row * NE + e)] : ei[(size_t)row * NE + e];
}

// ---- x (bf16 or f32) -> f32 workspace, 4 elems/thread ----
__global__ __launch_bounds__(256) void k_cvt_x(const void* __restrict__ xin,
                                               float* __restrict__ xf,
                                               const int* __restrict__ flags) {
  int i = blockIdx.x * 256 + threadIdx.x;   // exactly NN*CC/4 threads
  if (flags[0]) {
    const ushort4 v = ((const ushort4*)xin)[i];
    ((float4*)xf)[i] = make_float4(b2f(v.x), b2f(v.y), b2f(v.z), b2f(v.w));
  } else {
    ((float4*)xf)[i] = ((const float4*)xin)[i];
  }
}

// ---- params (lw, lb, emw, emb) -> f32 workspace ----
__global__ __launch_bounds__(256) void k_cvt_par(const void* lw, const void* lb,
                                                 const void* emw, const void* emb,
                                                 float* lwf, float* lbf,
                                                 float* emwf, float* embf,
                                                 const int* __restrict__ flags) {
  int i = blockIdx.x * 256 + threadIdx.x;
  const int bf = flags[0];
  if (i < NL * CC * CC)
    lwf[i] = bf ? b2f(((const unsigned short*)lw)[i]) : ((const float*)lw)[i];
  if (i < NL * CC)
    lbf[i] = bf ? b2f(((const unsigned short*)lb)[i]) : ((const float*)lb)[i];
  if (i < NL * 8)
    emwf[i] = bf ? b2f(((const unsigned short*)emw)[i]) : ((const float*)emw)[i];
  if (i < NL)
    embf[i] = bf ? b2f(((const unsigned short*)emb)[i]) : ((const float*)emb)[i];
}

// ---- CSR build: histogram of dst ----
__global__ __launch_bounds__(256) void k_hist(const int* __restrict__ ei,
                                              int* __restrict__ deg,
                                              const int* __restrict__ flags) {
  int e = blockIdx.x * 256 + threadIdx.x;
  if (e >= NE) return;
  atomicAdd(&deg[eidx(ei, 1, e, flags[1])], 1);
}

// ---- 3-phase device-wide exclusive scan over deg[NN] ----
// phase 1: 49 blocks x 256 threads x int4: in-block exclusive scan + block sums
#define NI4 (NN / 4)            // 12500 int4s
#define SCAN_BLKS ((NI4 + 255) / 256)   // 49
__global__ __launch_bounds__(256) void k_scan1(const int* __restrict__ deg,
                                               int* __restrict__ offs,
                                               int* __restrict__ bsum) {
  __shared__ int ls[256];
  const int t = threadIdx.x;
  const int g = blockIdx.x * 256 + t;
  int4 d = make_int4(0, 0, 0, 0);
  if (g < NI4) d = ((const int4*)deg)[g];
  const int s = d.x + d.y + d.z + d.w;
  ls[t] = s;
  __syncthreads();
#pragma unroll
  for (int off = 1; off < 256; off <<= 1) {
    int tmp = (t >= off) ? ls[t - off] : 0;
    __syncthreads();
    ls[t] += tmp;
    __syncthreads();
  }
  const int excl = ls[t] - s;   // exclusive prefix within block
  if (g < NI4) {
    int4 o;
    o.x = excl;
    o.y = o.x + d.x;
    o.z = o.y + d.y;
    o.w = o.z + d.z;
    ((int4*)offs)[g] = o;
  }
  if (t == 255) bsum[blockIdx.x] = ls[255];
}

// phase 2: serial scan of 49 block sums (trivial)
__global__ void k_scan2(const int* __restrict__ bsum, int* __restrict__ bbase,
                        int* __restrict__ offs) {
  if (threadIdx.x == 0) {
    int run = 0;
    for (int b = 0; b < SCAN_BLKS; ++b) { bbase[b] = run; run += bsum[b]; }
    offs[NN] = run;
  }
}

// phase 3: add block bases; materialize cursor
__global__ __launch_bounds__(256) void k_scan3(int* __restrict__ offs,
                                               int* __restrict__ cursor,
                                               const int* __restrict__ bbase) {
  const int g = blockIdx.x * 256 + threadIdx.x;
  if (g >= NI4) return;
  const int base = bbase[blockIdx.x];
  int4 o = ((int4*)offs)[g];
  o.x += base; o.y += base; o.z += base; o.w += base;
  ((int4*)offs)[g] = o;
  ((int4*)cursor)[g] = o;
}

// ---- CSR build: fill sorted src + per-edge rank ----
__global__ __launch_bounds__(256) void k_fill(const int* __restrict__ ei,
                                              int* __restrict__ cursor,
                                              int* __restrict__ rank,
                                              int* __restrict__ srcs,
                                              const int* __restrict__ flags) {
  int e = blockIdx.x * 256 + threadIdx.x;
  if (e >= NE) return;
  const int f64 = flags[1];
  int d = eidx(ei, 1, e, f64);
  int pos = atomicAdd(&cursor[d], 1);
  rank[e] = pos;
  srcs[pos] = eidx(ei, 0, e, f64);
}

// ---- per-edge weight: softplus(edge_attr . ew + eb) -> w_sorted[rank[e]] ----
__global__ __launch_bounds__(256) void k_edgew(const void* __restrict__ ea,
                                               const float* __restrict__ emwf,
                                               const float* __restrict__ embf,
                                               int layer,
                                               const int* __restrict__ rank,
                                               float* __restrict__ wsorted,
                                               const int* __restrict__ flags) {
  int e = blockIdx.x * 256 + threadIdx.x;
  if (e >= NE) return;
  float a[8];
  if (flags[0]) {                       // bf16: 8 attrs in 16B
    const uint4 v = ((const uint4*)ea)[e];
    unsigned int p[4] = {v.x, v.y, v.z, v.w};
#pragma unroll
    for (int q = 0; q < 4; ++q) {
      a[2 * q]     = __uint_as_float(p[q] << 16);
      a[2 * q + 1] = __uint_as_float(p[q] & 0xffff0000u);
    }
  } else {                              // f32: 8 attrs in 32B
    const float4 v0 = ((const float4*)ea)[2 * e];
    const float4 v1 = ((const float4*)ea)[2 * e + 1];
    a[0] = v0.x; a[1] = v0.y; a[2] = v0.z; a[3] = v0.w;
    a[4] = v1.x; a[5] = v1.y; a[6] = v1.z; a[7] = v1.w;
  }
  float z = embf[layer];
#pragma unroll
  for (int k = 0; k < 8; ++k) z += a[k] * emwf[layer * 8 + k];
  float w = (z > 20.f) ? z : log1pf(expf(z));   // softplus
  wsorted[rank[e]] = w;
}

// ---- gather: agg[n] = sum_{dst=n} w*x[src] - (sum w)*x[n]  (one wave/node) ----
__global__ __launch_bounds__(256) void k_gather(const int* __restrict__ offs,
                                                const int* __restrict__ srcs,
                                                const float* __restrict__ ws,
                                                const float* __restrict__ xf,
                                                float* __restrict__ agg) {
  const int node = blockIdx.x * 4 + (threadIdx.x >> 6);
  if (node >= NN) return;
  const int c = (threadIdx.x & 63) * 2;
  float ax = 0.f, ay = 0.f, sw = 0.f;
  int j = offs[node];
  const int j1 = offs[node + 1];
  for (; j + 4 <= j1; j += 4) {         // 4-edge unroll: 4 rows in flight
    const int s0 = srcs[j], s1 = srcs[j + 1], s2 = srcs[j + 2], s3 = srcs[j + 3];
    const float w0 = ws[j], w1 = ws[j + 1], w2 = ws[j + 2], w3 = ws[j + 3];
    const float2 v0 = *(const float2*)&xf[(size_t)s0 * CC + c];
    const float2 v1 = *(const float2*)&xf[(size_t)s1 * CC + c];
    const float2 v2 = *(const float2*)&xf[(size_t)s2 * CC + c];
    const float2 v3 = *(const float2*)&xf[(size_t)s3 * CC + c];
    ax += w0 * v0.x + w1 * v1.x + w2 * v2.x + w3 * v3.x;
    ay += w0 * v0.y + w1 * v1.y + w2 * v2.y + w3 * v3.y;
    sw += w0 + w1 + w2 + w3;
  }
  for (; j < j1; ++j) {
    const int s0 = srcs[j];
    const float w0 = ws[j];
    const float2 v0 = *(const float2*)&xf[(size_t)s0 * CC + c];
    ax += w0 * v0.x; ay += w0 * v0.y; sw += w0;
  }
  const float2 xi = *(const float2*)&xf[(size_t)node * CC + c];
  *(float2*)&agg[(size_t)node * CC + c] = make_float2(ax - sw * xi.x, ay - sw * xi.y);
}

// ---- gemm: y = agg @ lw + lb ; relu+residual in-place into agg,
//      or (last) store to d_out in detected dtype.
__global__ __launch_bounds__(256) void k_gemm(float* agg,
                                              const float* __restrict__ xc,
                                              const float* __restrict__ lwf,
                                              const float* __restrict__ lbf,
                                              int layer, void* outp, int last,
                                              const int* __restrict__ flags) {
  __shared__ float wsh[CC * CC];   // 64 KB f32 weights
  __shared__ float ash[16 * CC];   // 8 KB staged agg rows
  const float* lwp = lwf + (size_t)layer * CC * CC;
  for (int i = threadIdx.x; i < CC * CC / 4; i += 256)
    ((float4*)wsh)[i] = ((const float4*)lwp)[i];

  const int cg = threadIdx.x & 31;   // 4 cols at cg*4
  const int rs = threadIdx.x >> 5;   // row slot 0..7 (rows rs and rs+8)
  const int rb = blockIdx.x * 16;

  for (int i = threadIdx.x; i < 16 * CC / 4; i += 256)
    ((float4*)ash)[i] = *(const float4*)&agg[(size_t)rb * CC + (i << 2)];
  __syncthreads();

  float c0x = 0, c0y = 0, c0z = 0, c0w = 0;
  float c1x = 0, c1y = 0, c1z = 0, c1w = 0;
#pragma unroll 4
  for (int k = 0; k < CC; ++k) {
    const float a0 = ash[rs * CC + k];
    const float a1 = ash[(rs + 8) * CC + k];
    const float4 w = *(const float4*)&wsh[k * CC + (cg << 2)];
    c0x += a0 * w.x; c0y += a0 * w.y; c0z += a0 * w.z; c0w += a0 * w.w;
    c1x += a1 * w.x; c1y += a1 * w.y; c1z += a1 * w.z; c1w += a1 * w.w;
  }

  const float* lbp = lbf + layer * CC + (cg << 2);
  const float b0 = lbp[0], b1 = lbp[1], b2v = lbp[2], b3 = lbp[3];
  const int isbf = flags[0];

#pragma unroll
  for (int h = 0; h < 2; ++h) {
    const int r = rb + rs + h * 8;
    float y0 = (h ? c1x : c0x) + b0;
    float y1 = (h ? c1y : c0y) + b1;
    float y2 = (h ? c1z : c0z) + b2v;
    float y3 = (h ? c1w : c0w) + b3;
    const size_t off = (size_t)r * CC + (cg << 2);
    if (!last) {
      const float4 rv = *(const float4*)&xc[off];   // residual
      *(float4*)&agg[off] = make_float4(fmaxf(y0, 0.f) + rv.x, fmaxf(y1, 0.f) + rv.y,
                                        fmaxf(y2, 0.f) + rv.z, fmaxf(y3, 0.f) + rv.w);
    } else if (isbf) {
      *(uint2*)&((unsigned short*)outp)[off] =
          make_uint2((unsigned)f2b(y0) | ((unsigned)f2b(y1) << 16),
                     (unsigned)f2b(y2) | ((unsigned)f2b(y3) << 16));
    } else {
      *(float4*)&((float*)outp)[off] = make_float4(y0, y1, y2, y3);
    }
  }
}

extern "C" void kernel_launch(void* const* d_in, const int* in_sizes, int n_in,
                              void* d_out, int out_size, void* d_ws, size_t ws_size,
                              hipStream_t stream) {
  const unsigned short* x0 = (const unsigned short*)d_in[0];
  const int* ei = (const int*)d_in[1];

  // Workspace layout (all element offsets of vector-accessed arrays stay
  // 16B-aligned). Elements (f32/int):
  //   buf0 6.4M | buf1 6.4M | wsorted NE | deg NN | offs NN+4 | cursor NN |
  //   rank NE | srcs NE | bsum 64 | bbase 64 | lwf 49152 | lbf 384 |
  //   emwf 24 | embf 3 | flags 2
  const size_t nbuf = (size_t)NN * CC;
  float* buf0 = (float*)d_ws;
  float* buf1 = buf0 + nbuf;
  float* wsorted = buf1 + nbuf;
  int* deg = (int*)(wsorted + NE);
  int* offs = deg + NN;
  int* cursor = offs + NN + 4;        // +4 keeps cursor 16B-aligned
  int* rank = cursor + NN;
  int* srcs = rank + NE;
  int* bsum = srcs + NE;
  int* bbase = bsum + 64;
  float* lwf = (float*)(bbase + 64);
  float* lbf = lwf + (size_t)NL * CC * CC;
  float* emwf = lbf + (size_t)NL * CC;
  float* embf = emwf + NL * 8;
  int* flags = (int*)(embf + NL);
  const size_t need = (size_t)((int*)(flags + 2) - (int*)d_ws) * 4;
  if (ws_size < need) {
    hipMemsetAsync(d_out, 0, (size_t)out_size * 2, stream);
    return;
  }

  k_flags<<<1, 256, 0, stream>>>(x0, ei, flags);
  k_cvt_x<<<(NN * CC / 4) / 256, 256, 0, stream>>>(d_in[0], buf0, flags);
  k_cvt_par<<<(NL * CC * CC + 255) / 256, 256, 0, stream>>>(
      d_in[3], d_in[4], d_in[5], d_in[6], lwf, lbf, emwf, embf, flags);

  // CSR build (once per call; edge_index is call-invariant)
  hipMemsetAsync(deg, 0, NN * sizeof(int), stream);
  k_hist<<<(NE + 255) / 256, 256, 0, stream>>>(ei, deg, flags);
  k_scan1<<<SCAN_BLKS, 256, 0, stream>>>(deg, offs, bsum);
  k_scan2<<<1, 64, 0, stream>>>(bsum, bbase, offs);
  k_scan3<<<SCAN_BLKS, 256, 0, stream>>>(offs, cursor, bbase);
  k_fill<<<(NE + 255) / 256, 256, 0, stream>>>(ei, cursor, rank, srcs, flags);

  float* xc = buf0;   // current x
  float* ag = buf1;   // message buffer for this layer
  for (int layer = 0; layer < NL; ++layer) {
    k_edgew<<<(NE + 255) / 256, 256, 0, stream>>>(d_in[2], emwf, embf, layer,
                                                  rank, wsorted, flags);
    k_gather<<<(NN + 3) / 4, 256, 0, stream>>>(offs, srcs, wsorted, xc, ag);
    k_gemm<<<NN / 16, 256, 0, stream>>>(ag, xc, lwf, lbf, layer, d_out,
                                        layer == NL - 1 ? 1 : 0, flags);
    float* t = xc; xc = ag; ag = t;   // gemm wrote new x in-place into ag
  }
}

// Round 6
// 401.254 us; speedup vs baseline: 3.8837x; 1.4326x over previous
//
#include <hip/hip_runtime.h>

#define NN 50000
#define NE 800000
#define CC 128
#define NL 3

typedef short bf16x8 __attribute__((ext_vector_type(8)));
typedef float f32x4 __attribute__((ext_vector_type(4)));
union U16 { uint4 u; bf16x8 v; };

__device__ __forceinline__ float b2f(unsigned short u) {
  return __uint_as_float(((unsigned int)u) << 16);
}
__device__ __forceinline__ unsigned short f2b(float f) {
  unsigned int x = __float_as_uint(f);
  x += 0x7fffu + ((x >> 16) & 1u);   // round-to-nearest-even
  return (unsigned short)(x >> 16);
}

// flags[0] = 1 if float tensors are bf16, 0 if f32.
// flags[1] = 1 if edge_index is int64 (odd 32-bit words all zero), 0 if int32.
__global__ void k_flags(const unsigned short* __restrict__ x,
                        const int* __restrict__ ei, int* __restrict__ flags) {
  __shared__ int cnt, any;
  if (threadIdx.x == 0) { cnt = 0; any = 0; }
  __syncthreads();
  if (threadIdx.x < 128) {
    unsigned short u = x[2 * threadIdx.x];
    int ex = (u >> 7) & 0xFF;
    if (ex >= 0x70 && ex <= 0x8F) atomicAdd(&cnt, 1);
  }
  if (ei[2 * threadIdx.x + 1] != 0) atomicOr(&any, 1);
  __syncthreads();
  if (threadIdx.x == 0) {
    flags[0] = (cnt >= 64) ? 1 : 0;
    flags[1] = (any == 0) ? 1 : 0;
  }
}

__device__ __forceinline__ int eidx(const int* ei, int row, int e, int f64) {
  return f64 ? ei[2 * ((size_t)row * NE + e)] : ei[(size_t)row * NE + e];
}

// ---- x -> bf16 workspace (8 elems/thread) ----
__global__ __launch_bounds__(256) void k_cvt_x(const void* __restrict__ xin,
                                               unsigned short* __restrict__ xb,
                                               const int* __restrict__ flags) {
  int i = blockIdx.x * 256 + threadIdx.x;   // NN*CC/8 threads exactly
  if (flags[0]) {
    ((uint4*)xb)[i] = ((const uint4*)xin)[i];
  } else {
    const float4 a = ((const float4*)xin)[2 * i];
    const float4 b = ((const float4*)xin)[2 * i + 1];
    uint4 o;
    o.x = (unsigned)f2b(a.x) | ((unsigned)f2b(a.y) << 16);
    o.y = (unsigned)f2b(a.z) | ((unsigned)f2b(a.w) << 16);
    o.z = (unsigned)f2b(b.x) | ((unsigned)f2b(b.y) << 16);
    o.w = (unsigned)f2b(b.z) | ((unsigned)f2b(b.w) << 16);
    ((uint4*)xb)[i] = o;
  }
}

// ---- params: W transpose->bf16 (wt[l][n][k]), bias/emlp -> f32 ----
__global__ __launch_bounds__(256) void k_cvt_par(const void* lw, const void* lb,
                                                 const void* emw, const void* emb,
                                                 unsigned short* __restrict__ wt,
                                                 float* lbf, float* emwf, float* embf,
                                                 const int* __restrict__ flags) {
  int i = blockIdx.x * 256 + threadIdx.x;
  const int bf = flags[0];
  if (i < NL * CC * CC) {
    unsigned short v = bf ? ((const unsigned short*)lw)[i]
                          : f2b(((const float*)lw)[i]);
    const int l = i >> 14, r = i & 16383, k = r >> 7, n = r & 127;
    wt[l * 16384 + n * 128 + k] = v;
  }
  if (i < NL * CC)
    lbf[i] = bf ? b2f(((const unsigned short*)lb)[i]) : ((const float*)lb)[i];
  if (i < NL * 8)
    emwf[i] = bf ? b2f(((const unsigned short*)emw)[i]) : ((const float*)emw)[i];
  if (i < NL)
    embf[i] = bf ? b2f(((const unsigned short*)emb)[i]) : ((const float*)emb)[i];
}

// ---- CSR build: histogram of dst ----
__global__ __launch_bounds__(256) void k_hist(const int* __restrict__ ei,
                                              int* __restrict__ deg,
                                              const int* __restrict__ flags) {
  int e = blockIdx.x * 256 + threadIdx.x;
  if (e >= NE) return;
  atomicAdd(&deg[eidx(ei, 1, e, flags[1])], 1);
}

// ---- 3-phase device-wide exclusive scan over deg[NN] ----
#define NI4 (NN / 4)
#define SCAN_BLKS ((NI4 + 255) / 256)   // 49
__global__ __launch_bounds__(256) void k_scan1(const int* __restrict__ deg,
                                               int* __restrict__ offs,
                                               int* __restrict__ bsum) {
  __shared__ int ls[256];
  const int t = threadIdx.x;
  const int g = blockIdx.x * 256 + t;
  int4 d = make_int4(0, 0, 0, 0);
  if (g < NI4) d = ((const int4*)deg)[g];
  const int s = d.x + d.y + d.z + d.w;
  ls[t] = s;
  __syncthreads();
#pragma unroll
  for (int off = 1; off < 256; off <<= 1) {
    int tmp = (t >= off) ? ls[t - off] : 0;
    __syncthreads();
    ls[t] += tmp;
    __syncthreads();
  }
  const int excl = ls[t] - s;
  if (g < NI4) {
    int4 o;
    o.x = excl; o.y = o.x + d.x; o.z = o.y + d.y; o.w = o.z + d.z;
    ((int4*)offs)[g] = o;
  }
  if (t == 255) bsum[blockIdx.x] = ls[255];
}

__global__ void k_scan2(const int* __restrict__ bsum, int* __restrict__ bbase,
                        int* __restrict__ offs) {
  if (threadIdx.x == 0) {
    int run = 0;
    for (int b = 0; b < SCAN_BLKS; ++b) { bbase[b] = run; run += bsum[b]; }
    offs[NN] = run;
  }
}

__global__ __launch_bounds__(256) void k_scan3(int* __restrict__ offs,
                                               int* __restrict__ cursor,
                                               const int* __restrict__ bbase) {
  const int g = blockIdx.x * 256 + threadIdx.x;
  if (g >= NI4) return;
  const int base = bbase[blockIdx.x];
  int4 o = ((int4*)offs)[g];
  o.x += base; o.y += base; o.z += base; o.w += base;
  ((int4*)offs)[g] = o;
  ((int4*)cursor)[g] = o;
}

__global__ __launch_bounds__(256) void k_fill(const int* __restrict__ ei,
                                              int* __restrict__ cursor,
                                              int* __restrict__ rank,
                                              int* __restrict__ srcs,
                                              const int* __restrict__ flags) {
  int e = blockIdx.x * 256 + threadIdx.x;
  if (e >= NE) return;
  const int f64 = flags[1];
  int d = eidx(ei, 1, e, f64);
  int pos = atomicAdd(&cursor[d], 1);
  rank[e] = pos;
  srcs[pos] = eidx(ei, 0, e, f64);
}

// ---- per-edge weight: softplus(edge_attr . ew + eb) -> w_sorted[rank[e]] ----
__global__ __launch_bounds__(256) void k_edgew(const void* __restrict__ ea,
                                               const float* __restrict__ emwf,
                                               const float* __restrict__ embf,
                                               int layer,
                                               const int* __restrict__ rank,
                                               float* __restrict__ wsorted,
                                               const int* __restrict__ flags) {
  int e = blockIdx.x * 256 + threadIdx.x;
  if (e >= NE) return;
  float a[8];
  if (flags[0]) {
    const uint4 v = ((const uint4*)ea)[e];
    unsigned int p[4] = {v.x, v.y, v.z, v.w};
#pragma unroll
    for (int q = 0; q < 4; ++q) {
      a[2 * q]     = __uint_as_float(p[q] << 16);
      a[2 * q + 1] = __uint_as_float(p[q] & 0xffff0000u);
    }
  } else {
    const float4 v0 = ((const float4*)ea)[2 * e];
    const float4 v1 = ((const float4*)ea)[2 * e + 1];
    a[0] = v0.x; a[1] = v0.y; a[2] = v0.z; a[3] = v0.w;
    a[4] = v1.x; a[5] = v1.y; a[6] = v1.z; a[7] = v1.w;
  }
  float z = embf[layer];
#pragma unroll
  for (int k = 0; k < 8; ++k) z += a[k] * emwf[layer * 8 + k];
  float w = (z > 20.f) ? z : log1pf(expf(z));
  wsorted[rank[e]] = w;
}

// ---- gather (bf16): agg[n] = sum w*x[src] - (sum w)*x[n]; one wave/node ----
__global__ __launch_bounds__(256) void k_gather(const int* __restrict__ offs,
                                                const int* __restrict__ srcs,
                                                const float* __restrict__ ws,
                                                const unsigned short* __restrict__ xb,
                                                unsigned short* __restrict__ agg) {
  const int node = blockIdx.x * 4 + (threadIdx.x >> 6);
  const int c = (threadIdx.x & 63) * 2;
  float ax = 0.f, ay = 0.f, sw = 0.f;
  int j = offs[node];
  const int j1 = offs[node + 1];
  for (; j + 4 <= j1; j += 4) {
    const int s0 = srcs[j], s1 = srcs[j + 1], s2 = srcs[j + 2], s3 = srcs[j + 3];
    const float w0 = ws[j], w1 = ws[j + 1], w2 = ws[j + 2], w3 = ws[j + 3];
    const unsigned v0 = *(const unsigned*)&xb[(size_t)s0 * CC + c];
    const unsigned v1 = *(const unsigned*)&xb[(size_t)s1 * CC + c];
    const unsigned v2 = *(const unsigned*)&xb[(size_t)s2 * CC + c];
    const unsigned v3 = *(const unsigned*)&xb[(size_t)s3 * CC + c];
    ax += w0 * __uint_as_float(v0 << 16) + w1 * __uint_as_float(v1 << 16)
        + w2 * __uint_as_float(v2 << 16) + w3 * __uint_as_float(v3 << 16);
    ay += w0 * __uint_as_float(v0 & 0xffff0000u) + w1 * __uint_as_float(v1 & 0xffff0000u)
        + w2 * __uint_as_float(v2 & 0xffff0000u) + w3 * __uint_as_float(v3 & 0xffff0000u);
    sw += w0 + w1 + w2 + w3;
  }
  for (; j < j1; ++j) {
    const int s0 = srcs[j];
    const float w0 = ws[j];
    const unsigned v0 = *(const unsigned*)&xb[(size_t)s0 * CC + c];
    ax += w0 * __uint_as_float(v0 << 16);
    ay += w0 * __uint_as_float(v0 & 0xffff0000u);
    sw += w0;
  }
  const unsigned xi = *(const unsigned*)&xb[(size_t)node * CC + c];
  const float rx = ax - sw * __uint_as_float(xi << 16);
  const float ry = ay - sw * __uint_as_float(xi & 0xffff0000u);
  *(unsigned*)&agg[(size_t)node * CC + c] =
      (unsigned)f2b(rx) | ((unsigned)f2b(ry) << 16);
}

// ---- MFMA gemm: y = agg @ W + b; relu+residual -> xn (bf16), or final store.
// 256 threads (4 waves), 64 rows/block. LDS rows padded to 136 ushorts.
#define LPAD 136
__global__ __launch_bounds__(256) void k_gemm(unsigned short* agg,   // A and out rows
                                              const unsigned short* __restrict__ xc,
                                              const unsigned short* __restrict__ wt,
                                              const float* __restrict__ lbf,
                                              int layer, void* outp, int last,
                                              const int* __restrict__ flags) {
  __shared__ unsigned short shA[64 * LPAD];    // 17408 B
  __shared__ unsigned short shB[128 * LPAD];   // 34816 B
  const int rb = blockIdx.x * 64;
  const unsigned short* wtl = wt + (size_t)layer * CC * CC;

  // stage A (64 rows x 128 bf16) and B=W_t (128 x 128 bf16)
  for (int u = threadIdx.x; u < 1024; u += 256) {        // A: 64 rows x 16 uint4
    const int row = u >> 4, q = u & 15;
    uint4 v = make_uint4(0, 0, 0, 0);
    if (rb + row < NN) v = *(const uint4*)&agg[(size_t)(rb + row) * CC + q * 8];
    *(uint4*)&shA[row * LPAD + q * 8] = v;
  }
  for (int u = threadIdx.x; u < 2048; u += 256) {        // B: 128 rows x 16 uint4
    const int row = u >> 4, q = u & 15;
    *(uint4*)&shB[row * LPAD + q * 8] = *(const uint4*)&wtl[row * 128 + q * 8];
  }
  __syncthreads();

  const int w = threadIdx.x >> 6;    // wave 0..3 -> rows w*16..w*16+15
  const int l = threadIdx.x & 63;
  const int lr = l & 15;             // A row / B col within 16-tile
  const int lk = (l >> 4) * 8;       // k base (quad*8)

  U16 afr[4];
#pragma unroll
  for (int kk = 0; kk < 4; ++kk)
    afr[kk].u = *(const uint4*)&shA[(w * 16 + lr) * LPAD + kk * 32 + lk];

  const float* lbp = lbf + layer * CC;
  f32x4 acc[8];
#pragma unroll
  for (int t = 0; t < 8; ++t) {
    acc[t] = (f32x4){0.f, 0.f, 0.f, 0.f};
#pragma unroll
    for (int kk = 0; kk < 4; ++kk) {
      U16 bfr;
      bfr.u = *(const uint4*)&shB[(t * 16 + lr) * LPAD + kk * 32 + lk];
      acc[t] = __builtin_amdgcn_mfma_f32_16x16x32_bf16(afr[kk].v, bfr.v, acc[t], 0, 0, 0);
    }
  }

  // epilogue: +bias, bounce through shA (wave-private rows) for coalesced store
#pragma unroll
  for (int t = 0; t < 8; ++t) {
    const float bv = lbp[t * 16 + lr];   // col = t*16 + (l&15)
#pragma unroll
    for (int r = 0; r < 4; ++r) {
      const int tr = (l >> 4) * 4 + r;   // C/D: row = quad*4 + reg
      shA[(w * 16 + tr) * LPAD + t * 16 + lr] = f2b(acc[t][r] + bv);
    }
  }
  // wave-local LDS visibility only (same wave reads its own rows); compiler
  // inserts lgkmcnt waits. Coalesced readback: 2 rows per 64 lanes.
  const int isbf = flags[0];
#pragma unroll
  for (int i = 0; i < 8; ++i) {
    const int idx = i * 64 + l;          // 512 uint2-groups: 16 rows x 32
    const int row = idx >> 5, cg = idx & 31;
    const int gr = rb + w * 16 + row;
    if (gr >= NN) continue;
    const uint2 yv = *(const uint2*)&shA[(w * 16 + row) * LPAD + cg * 4];
    float y0 = __uint_as_float(yv.x << 16);
    float y1 = __uint_as_float(yv.x & 0xffff0000u);
    float y2 = __uint_as_float(yv.y << 16);
    float y3 = __uint_as_float(yv.y & 0xffff0000u);
    const size_t off = (size_t)gr * CC + cg * 4;
    if (!last) {
      const uint2 rv = *(const uint2*)&xc[off];
      y0 = fmaxf(y0, 0.f) + __uint_as_float(rv.x << 16);
      y1 = fmaxf(y1, 0.f) + __uint_as_float(rv.x & 0xffff0000u);
      y2 = fmaxf(y2, 0.f) + __uint_as_float(rv.y << 16);
      y3 = fmaxf(y3, 0.f) + __uint_as_float(rv.y & 0xffff0000u);
      *(uint2*)&agg[off] = make_uint2((unsigned)f2b(y0) | ((unsigned)f2b(y1) << 16),
                                      (unsigned)f2b(y2) | ((unsigned)f2b(y3) << 16));
    } else if (isbf) {
      *(uint2*)&((unsigned short*)outp)[off] = yv;
    } else {
      *(float4*)&((float*)outp)[off] = make_float4(y0, y1, y2, y3);
    }
  }
}

extern "C" void kernel_launch(void* const* d_in, const int* in_sizes, int n_in,
                              void* d_out, int out_size, void* d_ws, size_t ws_size,
                              hipStream_t stream) {
  const unsigned short* x0 = (const unsigned short*)d_in[0];
  const int* ei = (const int*)d_in[1];

  // workspace: xb0,xb1 bf16 | wt bf16 | wsorted f32 | deg/offs/cursor/rank/srcs |
  //            bsum/bbase | lbf/emwf/embf f32 | flags
  const size_t nbuf = (size_t)NN * CC;
  unsigned short* xb0 = (unsigned short*)d_ws;
  unsigned short* xb1 = xb0 + nbuf;
  unsigned short* wt = xb1 + nbuf;
  float* wsorted = (float*)(wt + (size_t)NL * CC * CC);
  int* deg = (int*)(wsorted + NE);
  int* offs = deg + NN;
  int* cursor = offs + NN + 4;
  int* rank = cursor + NN;
  int* srcs = rank + NE;
  int* bsum = srcs + NE;
  int* bbase = bsum + 64;
  float* lbf = (float*)(bbase + 64);
  float* emwf = lbf + (size_t)NL * CC;
  float* embf = emwf + NL * 8;
  int* flags = (int*)(embf + NL);
  const size_t need = (size_t)((char*)(flags + 2) - (char*)d_ws);
  if (ws_size < need) {
    hipMemsetAsync(d_out, 0, (size_t)out_size * 2, stream);
    return;
  }

  k_flags<<<1, 256, 0, stream>>>(x0, ei, flags);
  k_cvt_x<<<(NN * CC / 8) / 256, 256, 0, stream>>>(d_in[0], xb0, flags);
  k_cvt_par<<<(NL * CC * CC + 255) / 256, 256, 0, stream>>>(
      d_in[3], d_in[4], d_in[5], d_in[6], wt, lbf, emwf, embf, flags);

  hipMemsetAsync(deg, 0, NN * sizeof(int), stream);
  k_hist<<<(NE + 255) / 256, 256, 0, stream>>>(ei, deg, flags);
  k_scan1<<<SCAN_BLKS, 256, 0, stream>>>(deg, offs, bsum);
  k_scan2<<<1, 64, 0, stream>>>(bsum, bbase, offs);
  k_scan3<<<SCAN_BLKS, 256, 0, stream>>>(offs, cursor, bbase);
  k_fill<<<(NE + 255) / 256, 256, 0, stream>>>(ei, cursor, rank, srcs, flags);

  unsigned short* xc = xb0;
  unsigned short* ag = xb1;
  for (int layer = 0; layer < NL; ++layer) {
    k_edgew<<<(NE + 255) / 256, 256, 0, stream>>>(d_in[2], emwf, embf, layer,
                                                  rank, wsorted, flags);
    k_gather<<<NN / 4, 256, 0, stream>>>(offs, srcs, wsorted, xc, ag);
    k_gemm<<<(NN + 63) / 64, 256, 0, stream>>>(ag, xc, wt, lbf, layer, d_out,
                                               layer == NL - 1 ? 1 : 0, flags);
    unsigned short* t = xc; xc = ag; ag = t;   // gemm wrote new x into ag
  }
}

// Round 7
// 386.193 us; speedup vs baseline: 4.0351x; 1.0390x over previous
//
#include <hip/hip_runtime.h>

#define NN 50000
#define NE 800000
#define CC 128
#define NL 3

typedef short bf16x8 __attribute__((ext_vector_type(8)));
typedef float f32x4 __attribute__((ext_vector_type(4)));
union U16 { uint4 u; bf16x8 v; };

__device__ __forceinline__ float b2f(unsigned short u) {
  return __uint_as_float(((unsigned int)u) << 16);
}
__device__ __forceinline__ unsigned short f2b(float f) {
  unsigned int x = __float_as_uint(f);
  x += 0x7fffu + ((x >> 16) & 1u);   // round-to-nearest-even
  return (unsigned short)(x >> 16);
}

// flags[0] = 1 if float tensors are bf16, 0 if f32.
// flags[1] = 1 if edge_index is int64 (odd 32-bit words all zero), 0 if int32.
__global__ void k_flags(const unsigned short* __restrict__ x,
                        const int* __restrict__ ei, int* __restrict__ flags) {
  __shared__ int cnt, any;
  if (threadIdx.x == 0) { cnt = 0; any = 0; }
  __syncthreads();
  if (threadIdx.x < 128) {
    unsigned short u = x[2 * threadIdx.x];
    int ex = (u >> 7) & 0xFF;
    if (ex >= 0x70 && ex <= 0x8F) atomicAdd(&cnt, 1);
  }
  if (ei[2 * threadIdx.x + 1] != 0) atomicOr(&any, 1);
  __syncthreads();
  if (threadIdx.x == 0) {
    flags[0] = (cnt >= 64) ? 1 : 0;
    flags[1] = (any == 0) ? 1 : 0;
  }
}

__device__ __forceinline__ int eidx(const int* ei, int row, int e, int f64) {
  return f64 ? ei[2 * ((size_t)row * NE + e)] : ei[(size_t)row * NE + e];
}

// ---- x -> bf16 workspace; no-op in bf16 mode (layer 0 reads d_in[0] direct) ----
__global__ __launch_bounds__(256) void k_cvt_x(const void* __restrict__ xin,
                                               unsigned short* __restrict__ xb,
                                               const int* __restrict__ flags) {
  if (flags[0]) return;
  int i = blockIdx.x * 256 + threadIdx.x;   // NN*CC/8 threads exactly
  const float4 a = ((const float4*)xin)[2 * i];
  const float4 b = ((const float4*)xin)[2 * i + 1];
  uint4 o;
  o.x = (unsigned)f2b(a.x) | ((unsigned)f2b(a.y) << 16);
  o.y = (unsigned)f2b(a.z) | ((unsigned)f2b(a.w) << 16);
  o.z = (unsigned)f2b(b.x) | ((unsigned)f2b(b.y) << 16);
  o.w = (unsigned)f2b(b.z) | ((unsigned)f2b(b.w) << 16);
  ((uint4*)xb)[i] = o;
}

// ---- params: W transpose->bf16 (wt[l][n][k]), bias/emlp -> f32 ----
__global__ __launch_bounds__(256) void k_cvt_par(const void* lw, const void* lb,
                                                 const void* emw, const void* emb,
                                                 unsigned short* __restrict__ wt,
                                                 float* lbf, float* emwf, float* embf,
                                                 const int* __restrict__ flags) {
  int i = blockIdx.x * 256 + threadIdx.x;
  const int bf = flags[0];
  if (i < NL * CC * CC) {
    unsigned short v = bf ? ((const unsigned short*)lw)[i]
                          : f2b(((const float*)lw)[i]);
    const int l = i >> 14, r = i & 16383, k = r >> 7, n = r & 127;
    wt[l * 16384 + n * 128 + k] = v;
  }
  if (i < NL * CC)
    lbf[i] = bf ? b2f(((const unsigned short*)lb)[i]) : ((const float*)lb)[i];
  if (i < NL * 8)
    emwf[i] = bf ? b2f(((const unsigned short*)emw)[i]) : ((const float*)emw)[i];
  if (i < NL)
    embf[i] = bf ? b2f(((const unsigned short*)emb)[i]) : ((const float*)emb)[i];
}

// ---- CSR build: histogram of dst ----
__global__ __launch_bounds__(256) void k_hist(const int* __restrict__ ei,
                                              int* __restrict__ deg,
                                              const int* __restrict__ flags) {
  int e = blockIdx.x * 256 + threadIdx.x;
  if (e >= NE) return;
  atomicAdd(&deg[eidx(ei, 1, e, flags[1])], 1);
}

// ---- 3-phase device-wide exclusive scan over deg[NN] ----
#define NI4 (NN / 4)
#define SCAN_BLKS ((NI4 + 255) / 256)   // 49
__global__ __launch_bounds__(256) void k_scan1(const int* __restrict__ deg,
                                               int* __restrict__ offs,
                                               int* __restrict__ bsum) {
  __shared__ int ls[256];
  const int t = threadIdx.x;
  const int g = blockIdx.x * 256 + t;
  int4 d = make_int4(0, 0, 0, 0);
  if (g < NI4) d = ((const int4*)deg)[g];
  const int s = d.x + d.y + d.z + d.w;
  ls[t] = s;
  __syncthreads();
#pragma unroll
  for (int off = 1; off < 256; off <<= 1) {
    int tmp = (t >= off) ? ls[t - off] : 0;
    __syncthreads();
    ls[t] += tmp;
    __syncthreads();
  }
  const int excl = ls[t] - s;
  if (g < NI4) {
    int4 o;
    o.x = excl; o.y = o.x + d.x; o.z = o.y + d.y; o.w = o.z + d.z;
    ((int4*)offs)[g] = o;
  }
  if (t == 255) bsum[blockIdx.x] = ls[255];
}

__global__ void k_scan2(const int* __restrict__ bsum, int* __restrict__ bbase,
                        int* __restrict__ offs) {
  if (threadIdx.x == 0) {
    int run = 0;
    for (int b = 0; b < SCAN_BLKS; ++b) { bbase[b] = run; run += bsum[b]; }
    offs[NN] = run;
  }
}

__global__ __launch_bounds__(256) void k_scan3(int* __restrict__ offs,
                                               int* __restrict__ cursor,
                                               const int* __restrict__ bbase) {
  const int g = blockIdx.x * 256 + threadIdx.x;
  if (g >= NI4) return;
  const int base = bbase[blockIdx.x];
  int4 o = ((int4*)offs)[g];
  o.x += base; o.y += base; o.z += base; o.w += base;
  ((int4*)offs)[g] = o;
  ((int4*)cursor)[g] = o;
}

// ---- CSR fill + all-layer edge weights, one scattered 16B store per edge:
//      esrt[pos] = (src, w0, w1, w2) with wl = softplus(ea . ew_l + eb_l)
__global__ __launch_bounds__(256) void k_fill2(const int* __restrict__ ei,
                                               const void* __restrict__ ea,
                                               const float* __restrict__ emwf,
                                               const float* __restrict__ embf,
                                               int* __restrict__ cursor,
                                               uint4* __restrict__ esrt,
                                               const int* __restrict__ flags) {
  int e = blockIdx.x * 256 + threadIdx.x;
  if (e >= NE) return;
  float a[8];
  if (flags[0]) {
    const uint4 v = ((const uint4*)ea)[e];
    unsigned int p[4] = {v.x, v.y, v.z, v.w};
#pragma unroll
    for (int q = 0; q < 4; ++q) {
      a[2 * q]     = __uint_as_float(p[q] << 16);
      a[2 * q + 1] = __uint_as_float(p[q] & 0xffff0000u);
    }
  } else {
    const float4 v0 = ((const float4*)ea)[2 * e];
    const float4 v1 = ((const float4*)ea)[2 * e + 1];
    a[0] = v0.x; a[1] = v0.y; a[2] = v0.z; a[3] = v0.w;
    a[4] = v1.x; a[5] = v1.y; a[6] = v1.z; a[7] = v1.w;
  }
  float w[NL];
#pragma unroll
  for (int l = 0; l < NL; ++l) {
    float z = embf[l];
#pragma unroll
    for (int k = 0; k < 8; ++k) z += a[k] * emwf[l * 8 + k];
    w[l] = (z > 20.f) ? z : log1pf(expf(z));
  }
  const int f64 = flags[1];
  const int d = eidx(ei, 1, e, f64);
  const int s = eidx(ei, 0, e, f64);
  const int pos = atomicAdd(&cursor[d], 1);
  esrt[pos] = make_uint4((unsigned)s, __float_as_uint(w[0]),
                         __float_as_uint(w[1]), __float_as_uint(w[2]));
}

// ---- gather (bf16): agg[n] = sum w*x[src] - (sum w)*x[n]; one wave/node ----
__global__ __launch_bounds__(256) void k_gather(const int* __restrict__ offs,
                                                const uint4* __restrict__ esrt,
                                                const unsigned short* xb_,
                                                const unsigned short* alt,
                                                int sel, int layer,
                                                unsigned short* __restrict__ agg,
                                                const int* __restrict__ flags) {
  const unsigned short* xb = (sel && flags[0]) ? alt : xb_;
  const int node = blockIdx.x * 4 + (threadIdx.x >> 6);
  const int c = (threadIdx.x & 63) * 2;
  float ax = 0.f, ay = 0.f, sw = 0.f;
  int j = offs[node];
  const int j1 = offs[node + 1];
  for (; j + 4 <= j1; j += 4) {
    const uint4 p0 = esrt[j], p1 = esrt[j + 1], p2 = esrt[j + 2], p3 = esrt[j + 3];
    const float w0 = __uint_as_float(layer == 0 ? p0.y : (layer == 1 ? p0.z : p0.w));
    const float w1 = __uint_as_float(layer == 0 ? p1.y : (layer == 1 ? p1.z : p1.w));
    const float w2 = __uint_as_float(layer == 0 ? p2.y : (layer == 1 ? p2.z : p2.w));
    const float w3 = __uint_as_float(layer == 0 ? p3.y : (layer == 1 ? p3.z : p3.w));
    const unsigned v0 = *(const unsigned*)&xb[(size_t)p0.x * CC + c];
    const unsigned v1 = *(const unsigned*)&xb[(size_t)p1.x * CC + c];
    const unsigned v2 = *(const unsigned*)&xb[(size_t)p2.x * CC + c];
    const unsigned v3 = *(const unsigned*)&xb[(size_t)p3.x * CC + c];
    ax += w0 * __uint_as_float(v0 << 16) + w1 * __uint_as_float(v1 << 16)
        + w2 * __uint_as_float(v2 << 16) + w3 * __uint_as_float(v3 << 16);
    ay += w0 * __uint_as_float(v0 & 0xffff0000u) + w1 * __uint_as_float(v1 & 0xffff0000u)
        + w2 * __uint_as_float(v2 & 0xffff0000u) + w3 * __uint_as_float(v3 & 0xffff0000u);
    sw += w0 + w1 + w2 + w3;
  }
  for (; j < j1; ++j) {
    const uint4 p0 = esrt[j];
    const float w0 = __uint_as_float(layer == 0 ? p0.y : (layer == 1 ? p0.z : p0.w));
    const unsigned v0 = *(const unsigned*)&xb[(size_t)p0.x * CC + c];
    ax += w0 * __uint_as_float(v0 << 16);
    ay += w0 * __uint_as_float(v0 & 0xffff0000u);
    sw += w0;
  }
  const unsigned xi = *(const unsigned*)&xb[(size_t)node * CC + c];
  const float rx = ax - sw * __uint_as_float(xi << 16);
  const float ry = ay - sw * __uint_as_float(xi & 0xffff0000u);
  *(unsigned*)&agg[(size_t)node * CC + c] =
      (unsigned)f2b(rx) | ((unsigned)f2b(ry) << 16);
}

// ---- MFMA gemm: y = agg @ W + b; relu+residual -> in-place agg, or final store.
#define LPAD 136
__global__ __launch_bounds__(256) void k_gemm(unsigned short* agg,
                                              const unsigned short* xc_,
                                              const unsigned short* alt,
                                              int sel,
                                              const unsigned short* __restrict__ wt,
                                              const float* __restrict__ lbf,
                                              int layer, void* outp, int last,
                                              const int* __restrict__ flags) {
  const unsigned short* xc = (sel && flags[0]) ? alt : xc_;
  __shared__ unsigned short shA[64 * LPAD];    // 17408 B
  __shared__ unsigned short shB[128 * LPAD];   // 34816 B
  const int rb = blockIdx.x * 64;
  const unsigned short* wtl = wt + (size_t)layer * CC * CC;

  for (int u = threadIdx.x; u < 1024; u += 256) {        // A: 64 rows x 16 uint4
    const int row = u >> 4, q = u & 15;
    uint4 v = make_uint4(0, 0, 0, 0);
    if (rb + row < NN) v = *(const uint4*)&agg[(size_t)(rb + row) * CC + q * 8];
    *(uint4*)&shA[row * LPAD + q * 8] = v;
  }
  for (int u = threadIdx.x; u < 2048; u += 256) {        // B: 128 rows x 16 uint4
    const int row = u >> 4, q = u & 15;
    *(uint4*)&shB[row * LPAD + q * 8] = *(const uint4*)&wtl[row * 128 + q * 8];
  }
  __syncthreads();

  const int w = threadIdx.x >> 6;
  const int l = threadIdx.x & 63;
  const int lr = l & 15;
  const int lk = (l >> 4) * 8;

  U16 afr[4];
#pragma unroll
  for (int kk = 0; kk < 4; ++kk)
    afr[kk].u = *(const uint4*)&shA[(w * 16 + lr) * LPAD + kk * 32 + lk];

  const float* lbp = lbf + layer * CC;
  f32x4 acc[8];
#pragma unroll
  for (int t = 0; t < 8; ++t) {
    acc[t] = (f32x4){0.f, 0.f, 0.f, 0.f};
#pragma unroll
    for (int kk = 0; kk < 4; ++kk) {
      U16 bfr;
      bfr.u = *(const uint4*)&shB[(t * 16 + lr) * LPAD + kk * 32 + lk];
      acc[t] = __builtin_amdgcn_mfma_f32_16x16x32_bf16(afr[kk].v, bfr.v, acc[t], 0, 0, 0);
    }
  }

#pragma unroll
  for (int t = 0; t < 8; ++t) {
    const float bv = lbp[t * 16 + lr];
#pragma unroll
    for (int r = 0; r < 4; ++r) {
      const int tr = (l >> 4) * 4 + r;   // C/D: row = quad*4 + reg
      shA[(w * 16 + tr) * LPAD + t * 16 + lr] = f2b(acc[t][r] + bv);
    }
  }
  const int isbf = flags[0];
#pragma unroll
  for (int i = 0; i < 8; ++i) {
    const int idx = i * 64 + l;
    const int row = idx >> 5, cg = idx & 31;
    const int gr = rb + w * 16 + row;
    if (gr >= NN) continue;
    const uint2 yv = *(const uint2*)&shA[(w * 16 + row) * LPAD + cg * 4];
    float y0 = __uint_as_float(yv.x << 16);
    float y1 = __uint_as_float(yv.x & 0xffff0000u);
    float y2 = __uint_as_float(yv.y << 16);
    float y3 = __uint_as_float(yv.y & 0xffff0000u);
    const size_t off = (size_t)gr * CC + cg * 4;
    if (!last) {
      const uint2 rv = *(const uint2*)&xc[off];
      y0 = fmaxf(y0, 0.f) + __uint_as_float(rv.x << 16);
      y1 = fmaxf(y1, 0.f) + __uint_as_float(rv.x & 0xffff0000u);
      y2 = fmaxf(y2, 0.f) + __uint_as_float(rv.y << 16);
      y3 = fmaxf(y3, 0.f) + __uint_as_float(rv.y & 0xffff0000u);
      *(uint2*)&agg[off] = make_uint2((unsigned)f2b(y0) | ((unsigned)f2b(y1) << 16),
                                      (unsigned)f2b(y2) | ((unsigned)f2b(y3) << 16));
    } else if (isbf) {
      *(uint2*)&((unsigned short*)outp)[off] = yv;
    } else {
      *(float4*)&((float*)outp)[off] = make_float4(y0, y1, y2, y3);
    }
  }
}

extern "C" void kernel_launch(void* const* d_in, const int* in_sizes, int n_in,
                              void* d_out, int out_size, void* d_ws, size_t ws_size,
                              hipStream_t stream) {
  const unsigned short* x0 = (const unsigned short*)d_in[0];
  const int* ei = (const int*)d_in[1];

  // workspace: xb0,xb1 bf16 | wt bf16 | esrt uint4[NE] | deg/offs/cursor |
  //            bsum/bbase | lbf/emwf/embf f32 | flags   (~40 MB)
  const size_t nbuf = (size_t)NN * CC;
  unsigned short* xb0 = (unsigned short*)d_ws;
  unsigned short* xb1 = xb0 + nbuf;
  unsigned short* wt = xb1 + nbuf;
  uint4* esrt = (uint4*)(wt + (size_t)NL * CC * CC);
  int* deg = (int*)(esrt + NE);
  int* offs = deg + NN;
  int* cursor = offs + NN + 4;
  int* bsum = cursor + NN;
  int* bbase = bsum + 64;
  float* lbf = (float*)(bbase + 64);
  float* emwf = lbf + (size_t)NL * CC;
  float* embf = emwf + NL * 8;
  int* flags = (int*)(embf + NL);
  const size_t need = (size_t)((char*)(flags + 2) - (char*)d_ws);
  if (ws_size < need) {
    hipMemsetAsync(d_out, 0, (size_t)out_size * 2, stream);
    return;
  }

  k_flags<<<1, 256, 0, stream>>>(x0, ei, flags);
  k_cvt_x<<<(NN * CC / 8) / 256, 256, 0, stream>>>(d_in[0], xb0, flags);
  k_cvt_par<<<(NL * CC * CC + 255) / 256, 256, 0, stream>>>(
      d_in[3], d_in[4], d_in[5], d_in[6], wt, lbf, emwf, embf, flags);

  hipMemsetAsync(deg, 0, NN * sizeof(int), stream);
  k_hist<<<(NE + 255) / 256, 256, 0, stream>>>(ei, deg, flags);
  k_scan1<<<SCAN_BLKS, 256, 0, stream>>>(deg, offs, bsum);
  k_scan2<<<1, 64, 0, stream>>>(bsum, bbase, offs);
  k_scan3<<<SCAN_BLKS, 256, 0, stream>>>(offs, cursor, bbase);
  k_fill2<<<(NE + 255) / 256, 256, 0, stream>>>(ei, d_in[2], emwf, embf,
                                                cursor, esrt, flags);

  unsigned short* xc = xb0;
  unsigned short* ag = xb1;
  for (int layer = 0; layer < NL; ++layer) {
    const int sel = (layer == 0) ? 1 : 0;
    k_gather<<<NN / 4, 256, 0, stream>>>(offs, esrt, xc, x0, sel, layer, ag, flags);
    k_gemm<<<(NN + 63) / 64, 256, 0, stream>>>(ag, xc, x0, sel, wt, lbf, layer,
                                               d_out, layer == NL - 1 ? 1 : 0, flags);
    unsigned short* t = xc; xc = ag; ag = t;   // gemm wrote new x into ag
  }
}